// Round 6
// baseline (117.178 us; speedup 1.0000x reference)
//
#include <hip/hip_runtime.h>
#include <math.h>

#define EPS 1e-9f

constexpr int Bn = 1024, Dn = 512, Un = 512;
constexpr int BM = 64;      // rows of B per block (4x4 per thread)
constexpr int BU = 64;      // cols of U per block
constexpr int DK = 16;      // k-chunk staged in LDS (16KB/block)
constexpr int NTILES = (Bn / BM) * (Un / BU);   // 128 output tiles

typedef float v4f __attribute__((ext_vector_type(4)));

// Split-K semaphores: zero-initialized (.bss); last-arriving block resets its
// slot to 0, so the invariant "all zeros between launches" survives graph replay.
__device__ int tile_cnt[NTILES];

// XOR swizzle for sL columns (proven: conflicts -> 0). Multiples of 8,
// preserves b128 alignment of 4-float groups.
__device__ __forceinline__ int swz(int d) { return ((d >> 2) & 3) << 3; }

// Coherent 16B store: bypasses the non-coherent local L2 (sc0 sc1), but keeps
// full vector width -> wave-contiguous 256B segments, no write amplification
// (R3's scalar __hip_atomic_store partials: WRITE_SIZE 68.9MB vs 18MB ideal).
__device__ __forceinline__ void store_coherent_v4(float* addr, v4f v) {
    asm volatile("global_store_dwordx4 %0, %1, off sc0 sc1"
                 :: "v"(addr), "v"(v) : "memory");
}

// MODE 0: atomicAdd directly into out (small-ws fallback; out pre-zeroed)
// MODE 1: coherent dwordx4 partial stores + relaxed semaphore + fused tail.
//   Coherence recipe (hard-won R1->R4):
//   - NO __threadfence / acq-rel RMW in the hot path: they lower to
//     buffer_wbl2/buffer_inv per block (full local-L2 writeback+invalidate);
//     2048 of them mid-flight nuked every resident block's cached tiles
//     (47.6us -> 290us).
//   - writers: sc0/sc1 vector stores go straight to the coherent point; each
//     wave drains its own vmcnt before the barrier, so the relaxed semaphore
//     increment happens-after the data is globally visible.
//   - the ONE tail block per tile does a single agent-scope ACQUIRE (one
//     buffer_inv, 128 total near kernel end) then reads partials with cached
//     loads the compiler can pipeline.
// R6 change (single variable vs R4): __launch_bounds__(256,4) -> (256,8).
//   R4 measured VGPR=60 (< the 64 cap this imposes) and LDS 16.9KB x 8 =
//   135KB < 160KB, so 8 blocks/CU fit without restructuring. Grid 2048 ->
//   one residency round, 32 waves/CU (R4: 4/CU, two rounds, Occ 28.9%,
//   VALUBusy 68.5%, ~17us idle of 54.2us).
//   R5's four-changes-at-once restructure (BM=32/v2f/SPLITD=8/(256,8))
//   failed correctness; this isolates the occupancy variable alone.
template <int SPLITD, int MODE>
__global__ __launch_bounds__(256, 8) void power_layer(
    const float* __restrict__ x, const float* __restrict__ w,
    const float* __restrict__ p, const float* __restrict__ bias,
    float* __restrict__ outp, float* __restrict__ wsp)
{
    constexpr int DPB    = Dn / SPLITD;
    constexpr int NCHUNK = DPB / DK;

    __shared__ float sL[DK][BM];   // sign(neg)*(log2|x+eps|+64), swizzled cols
    __shared__ float sP[DK][BU];   // p
    __shared__ float sW[DK][BU];   // w
    __shared__ float sWX[DK][BU];  // odd(p) ? -w : w

    const int tid = threadIdx.x;
    const int tx  = tid & 15;
    const int ty  = tid >> 4;
    const int tx4 = tx * 4;
    const int ty4 = ty * 4;
    const int ub = blockIdx.x * BU;
    const int bb = blockIdx.y * BM;
    const int d0 = blockIdx.z * DPB;

    // staging thread->element maps (chunk-invariant)
    const int xr  = tid >> 2;          // 0..63  (row for x tile)
    const int xdq = (tid & 3) << 2;    // 0,4,8,12 (d quad for x tile)
    const int pd  = tid >> 4;          // 0..15  (d for p/w tile)
    const int puq = (tid & 15) << 2;   // 0..60  (u quad for p/w tile)

    float4 xv, pv, wv;                 // global->reg prefetch (software pipeline)

    auto load_chunk = [&](int ch) {
        const int db = d0 + ch * DK;
        xv = *reinterpret_cast<const float4*>(&x[(size_t)(bb + xr) * Dn + db + xdq]);
        const size_t gi = (size_t)(db + pd) * Un + ub + puq;
        pv = *reinterpret_cast<const float4*>(&p[gi]);
        wv = *reinterpret_cast<const float4*>(&w[gi]);
    };

    auto stage_chunk = [&]() {
        const float* xs = reinterpret_cast<const float*>(&xv);
        #pragma unroll
        for (int j = 0; j < 4; ++j) {
            const float xe = xs[j] + EPS;
            const float La = __builtin_amdgcn_logf(fabsf(xe)) + 64.0f;
            const int dd = xdq + j;
            sL[dd][xr ^ swz(dd)] = (xe < 0.0f) ? -La : La;
        }
        const float* ps  = reinterpret_cast<const float*>(&pv);
        const float* wsv = reinterpret_cast<const float*>(&wv);
        float4 wxv;
        float* wxs = reinterpret_cast<float*>(&wxv);
        #pragma unroll
        for (int j = 0; j < 4; ++j) {
            const bool odd = (fmodf(ps[j], 2.0f) != 0.0f);
            wxs[j] = odd ? -wsv[j] : wsv[j];
        }
        *reinterpret_cast<float4*>(&sP[pd][puq])  = pv;
        *reinterpret_cast<float4*>(&sW[pd][puq])  = wv;
        *reinterpret_cast<float4*>(&sWX[pd][puq]) = wxv;
    };

    v4f acc[4] = {};   // 4 rows x 4 cols per thread

    load_chunk(0);
    stage_chunk();
    __syncthreads();

    for (int ch = 0; ch < NCHUNK; ++ch) {
        // issue next chunk's global loads now; latency hides under 16 d-iters
        if (ch + 1 < NCHUNK) load_chunk(ch + 1);

        // R0-proven inner loop: read BOTH w arrays as true LDS (ds_read_b128)
        // and select per element with v_cndmask (never select a pointer ->
        // flat_load demotion, R1).
        #pragma unroll 2
        for (int d = 0; d < DK; ++d) {
            const v4f Lv = *reinterpret_cast<const v4f*>(&sL[d][ty4 ^ swz(d)]);
            const v4f Pv = *reinterpret_cast<const v4f*>(&sP[d][tx4]);
            const v4f Wv = *reinterpret_cast<const v4f*>(&sW[d][tx4]);
            const v4f Xv = *reinterpret_cast<const v4f*>(&sWX[d][tx4]);

            float Ld[4];
            bool  ng[4];
            #pragma unroll
            for (int r = 0; r < 4; ++r) {
                Ld[r] = fabsf(Lv[r]) - 64.0f;
                ng[r] = Lv[r] < 0.0f;
            }

            // batch all 16 independent exps before any consumer
            v4f e[4];
            #pragma unroll
            for (int r = 0; r < 4; ++r) {
                const v4f t = Pv * Ld[r];         // v_pk_mul_f32 x2
                #pragma unroll
                for (int c = 0; c < 4; ++c)
                    e[r][c] = __builtin_amdgcn_exp2f(t[c]);
            }

            #pragma unroll
            for (int r = 0; r < 4; ++r) {
                v4f wsel;
                #pragma unroll
                for (int c = 0; c < 4; ++c)
                    wsel[c] = ng[r] ? Xv[c] : Wv[c];   // v_cndmask
                acc[r] = __builtin_elementwise_fma(wsel, e[r], acc[r]);  // v_pk_fma x2
            }
        }
        __syncthreads();
        if (ch + 1 < NCHUNK) {
            stage_chunk();          // regs (loaded above) -> LDS
            __syncthreads();
        }
    }

    if (MODE == 0) {
        if (blockIdx.z == 0) {
            const v4f bv = *reinterpret_cast<const v4f*>(&bias[ub + tx4]);
            #pragma unroll
            for (int r = 0; r < 4; ++r)
                acc[r] += bv;
        }
        #pragma unroll
        for (int r = 0; r < 4; ++r) {
            const int row = bb + ty4 + r;
            #pragma unroll
            for (int c = 0; c < 4; ++c)
                atomicAdd(&outp[(size_t)row * Un + ub + tx4 + c], acc[r][c]);
        }
        return;
    }

    // ---- MODE 1: coherent vector partial stores, relaxed semaphore, tail ----
    {
        float* dst = wsp + (((size_t)blockIdx.z * Bn + bb + ty4) * Un + ub + tx4);
        #pragma unroll
        for (int r = 0; r < 4; ++r)
            store_coherent_v4(dst + (size_t)r * Un, acc[r]);
    }
    // each wave drains its own coherent stores; barrier then orders all waves'
    // drains before the semaphore increment.
    asm volatile("s_waitcnt vmcnt(0)" ::: "memory");
    __syncthreads();

    const int tile = blockIdx.y * (Un / BU) + blockIdx.x;
    __shared__ int s_last;
    if (tid == 0) {
        const int old = __hip_atomic_fetch_add(&tile_cnt[tile], 1,
                            __ATOMIC_RELAXED, __HIP_MEMORY_SCOPE_AGENT);
        s_last = (old == SPLITD - 1) ? 1 : 0;
        if (old == SPLITD - 1)     // self-clean for the next launch/replay
            __hip_atomic_store(&tile_cnt[tile], 0, __ATOMIC_RELAXED,
                               __HIP_MEMORY_SCOPE_AGENT);
    }
    __syncthreads();
    if (!s_last) return;

    // single agent-scope acquire: one buffer_inv per tail block (128 total,
    // at end of kernel life) -> local L1/L2 stale lines dropped; partials are
    // already at the coherent point (writers' sc0/sc1 stores + vmcnt drain
    // happened-before their semaphore increments).
    if (tid == 0)
        (void)__hip_atomic_load(&tile_cnt[tile], __ATOMIC_ACQUIRE,
                                __HIP_MEMORY_SCOPE_AGENT);
    __syncthreads();

    // normal cached dwordx4 loads: compiler pipelines them (64 per thread)
    const v4f bv = *reinterpret_cast<const v4f*>(&bias[ub + tx4]);
    v4f sum[4] = {bv, bv, bv, bv};
    const float* srcBase = wsp + ((size_t)(bb + ty4) * Un + ub + tx4);
    #pragma unroll 4
    for (int z = 0; z < SPLITD; ++z) {
        const float* src = srcBase + (size_t)z * Bn * Un;
        v4f t[4];
        #pragma unroll
        for (int r = 0; r < 4; ++r)
            t[r] = *reinterpret_cast<const v4f*>(src + (size_t)r * Un);
        #pragma unroll
        for (int r = 0; r < 4; ++r)
            sum[r] += t[r];
    }
    float* dsto = outp + ((size_t)(bb + ty4) * Un + ub + tx4);
    #pragma unroll
    for (int r = 0; r < 4; ++r)
        *reinterpret_cast<v4f*>(dsto + (size_t)r * Un) = sum[r];
}

extern "C" void kernel_launch(void* const* d_in, const int* in_sizes, int n_in,
                              void* d_out, int out_size, void* d_ws, size_t ws_size,
                              hipStream_t stream) {
    const float* x = (const float*)d_in[0];
    const float* w = (const float*)d_in[1];
    const float* p = (const float*)d_in[2];
    const float* b = (const float*)d_in[3];
    float* out = (float*)d_out;
    float* wsf = (float*)d_ws;

    const size_t need16 = (size_t)16 * Bn * Un * sizeof(float);   // 32 MB
    const size_t need8  = (size_t)8  * Bn * Un * sizeof(float);   // 16 MB
    const dim3 blk(256);

    if (ws_size >= need16) {
        // SPLITD=16: 8 x 16 x 16 = 2048 blocks; at (256,8) all co-resident
        // in ONE round (R4 at (256,4) needed two rounds, Occ 28.9%).
        power_layer<16, 1><<<dim3(Un / BU, Bn / BM, 16), blk, 0, stream>>>(x, w, p, b, out, wsf);
    } else if (ws_size >= need8) {
        power_layer<8, 1><<<dim3(Un / BU, Bn / BM, 8), blk, 0, stream>>>(x, w, p, b, out, wsf);
    } else {
        hipMemsetAsync(out, 0, (size_t)out_size * sizeof(float), stream);
        power_layer<8, 0><<<dim3(Un / BU, Bn / BM, 8), blk, 0, stream>>>(x, w, p, b, out, wsf);
    }
}

// Round 7
// 109.134 us; speedup vs baseline: 1.0737x; 1.0737x over previous
//
#include <hip/hip_runtime.h>
#include <math.h>

#define EPS 1e-9f

constexpr int Bn = 1024, Dn = 512, Un = 512;
constexpr int BM = 64;      // rows of B per block (4x4 per thread)
constexpr int BU = 64;      // cols of U per block
constexpr int DK = 16;      // k-chunk staged in LDS (16KB/block)

typedef float v4f __attribute__((ext_vector_type(4)));

// XOR swizzle for sL columns (R6-proven: conflicts -> 0). Multiples of 8,
// preserves b128 alignment of 4-float groups.
__device__ __forceinline__ int swz(int d) { return ((d >> 2) & 3) << 3; }

// Session findings baked in (R1-R6):
//  - Fused split-K tail (sc0/sc1 stores + semaphore) costs +6.6us in-kernel
//    but the separate reduce_ws launch costs only ~1.3us beyond fixed harness
//    overhead -> two-kernel structure wins. (R4 vs R0 accounting)
//  - __threadfence / acq-rel RMW in-flight = buffer_wbl2/buffer_inv storm,
//    47.6 -> 290us. Never again. (R1/R2)
//  - LDS reads must be compile-time addrspace(3): selecting a pointer demotes
//    to flat_load. Select VALUES with v_cndmask. (R1)
//  - VGPR <= 32 schedules serialize the 16-exp batch: (256,8) forced VGPR=32,
//    busy 68.5 -> 61%. Keep the register budget >= ~48. (R2/R6)
// R7 single change vs R0: __launch_bounds__(256,4) -> (256,6).
//    6 blocks/CU (LDS 16.9KB x 6 = 101KB < 160KB), VGPR cap ~85 >> 60 so the
//    batched-exp schedule is safe; 24 waves/CU vs 16 to cover barriers,
//    prologue global latency, and the staging log2 burst (R0: busy 74%,
//    idle 26%, Occ 35%).
template <int SPLITD, bool USE_WS>
__global__ __launch_bounds__(256, 6) void power_layer(
    const float* __restrict__ x, const float* __restrict__ w,
    const float* __restrict__ p, const float* __restrict__ bias,
    float* __restrict__ outp)
{
    constexpr int DPB    = Dn / SPLITD;
    constexpr int NCHUNK = DPB / DK;

    __shared__ float sL[DK][BM];   // Lenc = sign(neg)*(log2|x+eps|+64), swizzled cols
    __shared__ float sP[DK][BU];   // p
    __shared__ float sW[DK][BU];   // w
    __shared__ float sWX[DK][BU];  // odd(p) ? -w : w

    const int tid = threadIdx.x;
    const int tx  = tid & 15;
    const int ty  = tid >> 4;
    const int tx4 = tx * 4;
    const int ty4 = ty * 4;
    const int ub = blockIdx.x * BU;
    const int bb = blockIdx.y * BM;
    const int d0 = blockIdx.z * DPB;

    v4f acc[4] = {};   // 4 rows x 4 cols per thread

    for (int ch = 0; ch < NCHUNK; ++ch) {
        const int db = d0 + ch * DK;

        // ---- stage x tile -> sL (64 rows x 16 d, transposed+swizzled) ----
        // 256 float4 loads, 1 per thread.
        {
            const int r  = tid >> 2;          // 0..63
            const int dq = (tid & 3) << 2;    // 0,4,8,12
            const float4 xv = *reinterpret_cast<const float4*>(
                &x[(size_t)(bb + r) * Dn + db + dq]);
            const float* xs = reinterpret_cast<const float*>(&xv);
            #pragma unroll
            for (int j = 0; j < 4; ++j) {
                const float xe = xs[j] + EPS;
                const float La = __builtin_amdgcn_logf(fabsf(xe)) + 64.0f;
                const int dd = dq + j;
                sL[dd][r ^ swz(dd)] = (xe < 0.0f) ? -La : La;
            }
        }
        // ---- stage p,w tiles (16 d x 64 u, natural layout, 1 float4/thread) ----
        {
            const int d  = tid >> 4;          // 0..15
            const int uq = (tid & 15) << 2;   // 0..60
            const size_t gi = (size_t)(db + d) * Un + ub + uq;
            const float4 pv = *reinterpret_cast<const float4*>(&p[gi]);
            const float4 wv = *reinterpret_cast<const float4*>(&w[gi]);
            const float* ps  = reinterpret_cast<const float*>(&pv);
            const float* wsv = reinterpret_cast<const float*>(&wv);
            float4 wxv;
            float* wxs = reinterpret_cast<float*>(&wxv);
            #pragma unroll
            for (int j = 0; j < 4; ++j) {
                const bool odd = (fmodf(ps[j], 2.0f) != 0.0f);
                wxs[j] = odd ? -wsv[j] : wsv[j];
            }
            *reinterpret_cast<float4*>(&sP[d][uq])  = pv;
            *reinterpret_cast<float4*>(&sW[d][uq])  = wv;
            *reinterpret_cast<float4*>(&sWX[d][uq]) = wxv;
        }
        __syncthreads();

        // ---- inner loop: 4 b128 reads per d feed 16 elements/thread ----
        #pragma unroll 2
        for (int d = 0; d < DK; ++d) {
            const v4f Lv = *reinterpret_cast<const v4f*>(&sL[d][ty4 ^ swz(d)]);
            const v4f Pv = *reinterpret_cast<const v4f*>(&sP[d][tx4]);
            const v4f Wv = *reinterpret_cast<const v4f*>(&sW[d][tx4]);
            const v4f Xv = *reinterpret_cast<const v4f*>(&sWX[d][tx4]);

            float Ld[4];
            bool  ng[4];
            #pragma unroll
            for (int r = 0; r < 4; ++r) {
                Ld[r] = fabsf(Lv[r]) - 64.0f;
                ng[r] = Lv[r] < 0.0f;
            }

            // batch all 16 independent exps before any consumer
            v4f e[4];
            #pragma unroll
            for (int r = 0; r < 4; ++r) {
                const v4f t = Pv * Ld[r];         // v_pk_mul_f32 x2
                #pragma unroll
                for (int c = 0; c < 4; ++c)
                    e[r][c] = __builtin_amdgcn_exp2f(t[c]);
            }

            #pragma unroll
            for (int r = 0; r < 4; ++r) {
                v4f wsel;
                #pragma unroll
                for (int c = 0; c < 4; ++c)
                    wsel[c] = ng[r] ? Xv[c] : Wv[c];   // v_cndmask
                acc[r] = __builtin_elementwise_fma(wsel, e[r], acc[r]);  // v_pk_fma x2
            }
        }
        __syncthreads();
    }

    if (USE_WS) {
        // plain coalesced partial stores: ws[z][b][u]
        float* dst = outp + ((size_t)blockIdx.z * Bn + bb + ty4) * Un + ub + tx4;
        #pragma unroll
        for (int r = 0; r < 4; ++r)
            *reinterpret_cast<v4f*>(dst + (size_t)r * Un) = acc[r];
    } else {
        if (blockIdx.z == 0) {
            const v4f bv = *reinterpret_cast<const v4f*>(&bias[ub + tx4]);
            #pragma unroll
            for (int r = 0; r < 4; ++r)
                acc[r] += bv;
        }
        #pragma unroll
        for (int r = 0; r < 4; ++r) {
            const int row = bb + ty4 + r;
            #pragma unroll
            for (int c = 0; c < 4; ++c)
                atomicAdd(&outp[(size_t)row * Un + ub + tx4 + c], acc[r][c]);
        }
    }
}

// out[b,u] = sum_z ws[z][b][u] + bias[u]   (float4 per thread)
template <int SPLITD>
__global__ __launch_bounds__(256) void reduce_ws(
    const float* __restrict__ ws, const float* __restrict__ bias,
    float* __restrict__ out)
{
    const int nf4 = (Bn * Un) / 4;   // 131072
    const int i = blockIdx.x * 256 + threadIdx.x;
    if (i >= nf4) return;
    const v4f* w4 = reinterpret_cast<const v4f*>(ws);
    v4f a = w4[i];
    #pragma unroll
    for (int z = 1; z < SPLITD; ++z)
        a += w4[(size_t)z * nf4 + i];
    a += reinterpret_cast<const v4f*>(bias)[i & (Un / 4 - 1)];
    reinterpret_cast<v4f*>(out)[i] = a;
}

extern "C" void kernel_launch(void* const* d_in, const int* in_sizes, int n_in,
                              void* d_out, int out_size, void* d_ws, size_t ws_size,
                              hipStream_t stream) {
    const float* x = (const float*)d_in[0];
    const float* w = (const float*)d_in[1];
    const float* p = (const float*)d_in[2];
    const float* b = (const float*)d_in[3];
    float* out = (float*)d_out;

    const size_t need16 = (size_t)16 * Bn * Un * sizeof(float);   // 32 MB
    const size_t need8  = (size_t)8  * Bn * Un * sizeof(float);   // 16 MB
    const dim3 blk(256);
    const dim3 rgrid((Bn * Un / 4 + 255) / 256);

    if (ws_size >= need16) {
        // 8 x 16 x 16 = 2048 blocks
        float* wsf = (float*)d_ws;
        power_layer<16, true><<<dim3(Un / BU, Bn / BM, 16), blk, 0, stream>>>(x, w, p, b, wsf);
        reduce_ws<16><<<rgrid, blk, 0, stream>>>(wsf, b, out);
    } else if (ws_size >= need8) {
        float* wsf = (float*)d_ws;
        power_layer<8, true><<<dim3(Un / BU, Bn / BM, 8), blk, 0, stream>>>(x, w, p, b, wsf);
        reduce_ws<8><<<rgrid, blk, 0, stream>>>(wsf, b, out);
    } else {
        hipMemsetAsync(out, 0, (size_t)out_size * sizeof(float), stream);
        power_layer<8, false><<<dim3(Un / BU, Bn / BM, 8), blk, 0, stream>>>(x, w, p, b, out);
    }
}

// Round 8
// 107.496 us; speedup vs baseline: 1.0901x; 1.0152x over previous
//
#include <hip/hip_runtime.h>
#include <math.h>

#define EPS 1e-9f

constexpr int Bn = 1024, Dn = 512, Un = 512;
constexpr int BM = 64;      // rows of B per block (4x4 per thread)
constexpr int BU = 64;      // cols of U per block
constexpr int DK = 32;      // k-chunk staged in LDS (32KB/block) [R8: 16->32]

typedef float v4f __attribute__((ext_vector_type(4)));

// XOR swizzle for sL columns (proven: conflicts -> 0). Multiples of 8,
// preserves b128 alignment of 4-float groups. Period 16 in d -> identical
// bank behavior for DK=32.
__device__ __forceinline__ int swz(int d) { return ((d >> 2) & 3) << 3; }

// Session findings baked in (R1-R7):
//  - Two-kernel structure wins: fused split-K tail costs +6.6us in-kernel,
//    separate reduce_ws costs ~1.3us beyond fixed overhead. (R4 vs R0)
//  - NO __threadfence/acq-rel in-flight: buffer_wbl2/inv storm, 6x slower. (R1/R2)
//  - LDS reads must be compile-time addrspace(3): selecting a pointer
//    demotes to flat_load. Select VALUES with v_cndmask. (R1)
//  - launch_bounds waves-per-EU > 4 makes the allocator cut VGPR below the
//    ~48 the 16-exp batch needs: (256,8)->VGPR32 busy61%, (256,6)->VGPR40
//    busy69%. (256,4) with natural 48-60 VGPR is the optimum. (R6/R7)
// R8 single change vs R0: DK 16->32 (NCHUNK=1 at SPLITD=16): one staging
//    phase + ONE barrier per block instead of two full stage/sync cycles;
//    single 6-float4 burst per thread maximizes MLP; trailing barrier gone.
template <int SPLITD, bool USE_WS>
__global__ __launch_bounds__(256, 4) void power_layer(
    const float* __restrict__ x, const float* __restrict__ w,
    const float* __restrict__ p, const float* __restrict__ bias,
    float* __restrict__ outp)
{
    constexpr int DPB    = Dn / SPLITD;
    constexpr int NCHUNK = DPB / DK;   // 1 for SPLITD=16, 2 for SPLITD=8

    __shared__ float sL[DK][BM];   // Lenc = sign(neg)*(log2|x+eps|+64), swizzled cols
    __shared__ float sP[DK][BU];   // p
    __shared__ float sW[DK][BU];   // w
    __shared__ float sWX[DK][BU];  // odd(p) ? -w : w

    const int tid = threadIdx.x;
    const int tx  = tid & 15;
    const int ty  = tid >> 4;
    const int tx4 = tx * 4;
    const int ty4 = ty * 4;
    const int ub = blockIdx.x * BU;
    const int bb = blockIdx.y * BM;
    const int d0 = blockIdx.z * DPB;

    v4f acc[4] = {};   // 4 rows x 4 cols per thread

    for (int ch = 0; ch < NCHUNK; ++ch) {
        const int db = d0 + ch * DK;

        // ---- stage x tile -> sL (64 rows x 32 d, transposed+swizzled) ----
        // 512 float4 loads, 2 per thread (rows r and r+32).
        {
            const int r  = tid >> 3;          // 0..31
            const int dq = (tid & 7) << 2;    // 0,4,..,28
            const float4 xv0 = *reinterpret_cast<const float4*>(
                &x[(size_t)(bb + r) * Dn + db + dq]);
            const float4 xv1 = *reinterpret_cast<const float4*>(
                &x[(size_t)(bb + r + 32) * Dn + db + dq]);
            const float* xs0 = reinterpret_cast<const float*>(&xv0);
            const float* xs1 = reinterpret_cast<const float*>(&xv1);
            #pragma unroll
            for (int j = 0; j < 4; ++j) {
                const int dd = dq + j;
                {
                    const float xe = xs0[j] + EPS;
                    const float La = __builtin_amdgcn_logf(fabsf(xe)) + 64.0f;
                    sL[dd][r ^ swz(dd)] = (xe < 0.0f) ? -La : La;
                }
                {
                    const float xe = xs1[j] + EPS;
                    const float La = __builtin_amdgcn_logf(fabsf(xe)) + 64.0f;
                    sL[dd][(r + 32) ^ swz(dd)] = (xe < 0.0f) ? -La : La;
                }
            }
        }
        // ---- stage p,w tiles (32 d x 64 u, natural layout, 2 float4/thread each) ----
        {
            const int d  = tid >> 4;          // 0..15 (and d+16)
            const int uq = (tid & 15) << 2;   // 0..60
            #pragma unroll
            for (int h = 0; h < 2; ++h) {
                const int dd = d + h * 16;
                const size_t gi = (size_t)(db + dd) * Un + ub + uq;
                const float4 pv = *reinterpret_cast<const float4*>(&p[gi]);
                const float4 wv = *reinterpret_cast<const float4*>(&w[gi]);
                const float* ps  = reinterpret_cast<const float*>(&pv);
                const float* wsv = reinterpret_cast<const float*>(&wv);
                float4 wxv;
                float* wxs = reinterpret_cast<float*>(&wxv);
                #pragma unroll
                for (int j = 0; j < 4; ++j) {
                    const bool odd = (fmodf(ps[j], 2.0f) != 0.0f);
                    wxs[j] = odd ? -wsv[j] : wsv[j];
                }
                *reinterpret_cast<float4*>(&sP[dd][uq])  = pv;
                *reinterpret_cast<float4*>(&sW[dd][uq])  = wv;
                *reinterpret_cast<float4*>(&sWX[dd][uq]) = wxv;
            }
        }
        __syncthreads();

        // ---- inner loop: 4 b128 reads per d feed 16 elements/thread ----
        #pragma unroll 2
        for (int d = 0; d < DK; ++d) {
            const v4f Lv = *reinterpret_cast<const v4f*>(&sL[d][ty4 ^ swz(d)]);
            const v4f Pv = *reinterpret_cast<const v4f*>(&sP[d][tx4]);
            const v4f Wv = *reinterpret_cast<const v4f*>(&sW[d][tx4]);
            const v4f Xv = *reinterpret_cast<const v4f*>(&sWX[d][tx4]);

            float Ld[4];
            bool  ng[4];
            #pragma unroll
            for (int r = 0; r < 4; ++r) {
                Ld[r] = fabsf(Lv[r]) - 64.0f;
                ng[r] = Lv[r] < 0.0f;
            }

            // batch all 16 independent exps before any consumer
            v4f e[4];
            #pragma unroll
            for (int r = 0; r < 4; ++r) {
                const v4f t = Pv * Ld[r];         // v_pk_mul_f32 x2
                #pragma unroll
                for (int c = 0; c < 4; ++c)
                    e[r][c] = __builtin_amdgcn_exp2f(t[c]);
            }

            #pragma unroll
            for (int r = 0; r < 4; ++r) {
                v4f wsel;
                #pragma unroll
                for (int c = 0; c < 4; ++c)
                    wsel[c] = ng[r] ? Xv[c] : Wv[c];   // v_cndmask
                acc[r] = __builtin_elementwise_fma(wsel, e[r], acc[r]);  // v_pk_fma x2
            }
        }
        if (ch + 1 < NCHUNK) __syncthreads();   // only needed before re-staging
    }

    if (USE_WS) {
        // plain coalesced partial stores: ws[z][b][u]
        float* dst = outp + ((size_t)blockIdx.z * Bn + bb + ty4) * Un + ub + tx4;
        #pragma unroll
        for (int r = 0; r < 4; ++r)
            *reinterpret_cast<v4f*>(dst + (size_t)r * Un) = acc[r];
    } else {
        if (blockIdx.z == 0) {
            const v4f bv = *reinterpret_cast<const v4f*>(&bias[ub + tx4]);
            #pragma unroll
            for (int r = 0; r < 4; ++r)
                acc[r] += bv;
        }
        #pragma unroll
        for (int r = 0; r < 4; ++r) {
            const int row = bb + ty4 + r;
            #pragma unroll
            for (int c = 0; c < 4; ++c)
                atomicAdd(&outp[(size_t)row * Un + ub + tx4 + c], acc[r][c]);
        }
    }
}

// out[b,u] = sum_z ws[z][b][u] + bias[u]   (float4 per thread)
template <int SPLITD>
__global__ __launch_bounds__(256) void reduce_ws(
    const float* __restrict__ ws, const float* __restrict__ bias,
    float* __restrict__ out)
{
    const int nf4 = (Bn * Un) / 4;   // 131072
    const int i = blockIdx.x * 256 + threadIdx.x;
    if (i >= nf4) return;
    const v4f* w4 = reinterpret_cast<const v4f*>(ws);
    v4f a = w4[i];
    #pragma unroll
    for (int z = 1; z < SPLITD; ++z)
        a += w4[(size_t)z * nf4 + i];
    a += reinterpret_cast<const v4f*>(bias)[i & (Un / 4 - 1)];
    reinterpret_cast<v4f*>(out)[i] = a;
}

extern "C" void kernel_launch(void* const* d_in, const int* in_sizes, int n_in,
                              void* d_out, int out_size, void* d_ws, size_t ws_size,
                              hipStream_t stream) {
    const float* x = (const float*)d_in[0];
    const float* w = (const float*)d_in[1];
    const float* p = (const float*)d_in[2];
    const float* b = (const float*)d_in[3];
    float* out = (float*)d_out;

    const size_t need16 = (size_t)16 * Bn * Un * sizeof(float);   // 32 MB
    const size_t need8  = (size_t)8  * Bn * Un * sizeof(float);   // 16 MB
    const dim3 blk(256);
    const dim3 rgrid((Bn * Un / 4 + 255) / 256);

    if (ws_size >= need16) {
        // 8 x 16 x 16 = 2048 blocks; DPB=32=DK -> single-chunk blocks
        float* wsf = (float*)d_ws;
        power_layer<16, true><<<dim3(Un / BU, Bn / BM, 16), blk, 0, stream>>>(x, w, p, b, wsf);
        reduce_ws<16><<<rgrid, blk, 0, stream>>>(wsf, b, out);
    } else if (ws_size >= need8) {
        float* wsf = (float*)d_ws;
        power_layer<8, true><<<dim3(Un / BU, Bn / BM, 8), blk, 0, stream>>>(x, w, p, b, wsf);
        reduce_ws<8><<<rgrid, blk, 0, stream>>>(wsf, b, out);
    } else {
        hipMemsetAsync(out, 0, (size_t)out_size * sizeof(float), stream);
        power_layer<8, false><<<dim3(Un / BU, Bn / BM, 8), blk, 0, stream>>>(x, w, p, b, out);
    }
}